// Round 5
// baseline (392.492 us; speedup 1.0000x reference)
//
#include <hip/hip_runtime.h>
#include <hip/hip_bf16.h>

#define Bb 128
#define LQ 32
#define LD 512
#define Hh 768
#define Cc 128

#define DBLOCKS ((Bb * LD) / 64)   // 1024 doc blocks (64 rows each)

typedef short bf16x8 __attribute__((ext_vector_type(8)));
typedef float f32x4 __attribute__((ext_vector_type(4)));

__device__ __forceinline__ short f2bf(float f) {
  union { float f; unsigned u; } v;
  v.f = f;
  unsigned u = v.u + (0x7FFFu + ((v.u >> 16) & 1u));  // RNE
  return (short)(u >> 16);
}

// K0: W (H,C) fp32 -> Wt (C,H) bf16 (transposed so B fragments are
// row-contiguous bf16x8 loads straight from L2).
__global__ __launch_bounds__(256) void k_wt(const float* __restrict__ W,
                                            short* __restrict__ Wt) {
  int idx = blockIdx.x * 256 + threadIdx.x;  // grid covers H*C exactly
  int h = idx >> 7;   // / 128
  int c = idx & 127;
  Wt[c * Hh + h] = f2bf(W[idx]);
}

// Fully fused, ZERO-barrier K-loop.
// One block per (batch, 64-doc-token chunk); 4 waves, each owning a 16-row
// doc A-strip (waves 0-1 additionally own 16 q rows).
//
// Round-4 post-mortem: the 2-barrier-per-K-step LDS-staged loop ran with
// MfmaUtil 4% / VALU 17% / HBM 12% -- pure lockstep latency. The A-tile was
// wave-private (barriers existed only to share the B-tile), and B (Wt) is a
// 192 KB L2-resident constant. So: read BOTH A and B fragments directly from
// global memory in the exact MFMA fragment mapping (identical f2bf + MFMA
// sequence -> bit-identical results), and delete every __syncthreads from
// the K-loop. Waves free-run; L2 fb latency is hidden by 8-deep load batches
// and 12 resident waves/CU. LDS is used only for the dv/lq tiles + score
// phase (proven round-3 formulation, unchanged).
//
// LDS: dvt 33792 + lqt 16896 + dmsk 256 + pm 2048 = 52992 B -> 3 blocks/CU.
__global__ __launch_bounds__(256, 3) void k_fused(
    const float* __restrict__ dh, const float* __restrict__ qh,
    const short* __restrict__ Wt, const float* __restrict__ bcomp,
    const int* __restrict__ qmask, const int* __restrict__ dmask,
    const float* __restrict__ wstop, const float* __restrict__ bstop,
    float* __restrict__ partial) {
  constexpr int DSTR = 132;          // fp32 row stride (+4 pad: 2-way max)
  __shared__ __align__(16) float dvt[64 * DSTR];  // 33792 B
  __shared__ __align__(16) float lqt[32 * DSTR];  // 16896 B
  __shared__ int dmsk[64];
  __shared__ float pm[LQ * 16];

  const int tid = threadIdx.x;
  const int w = tid >> 6;
  const int lane = tid & 63;
  const int quad = lane >> 4;
  const int lm = lane & 15;
  const bool isq = (w < 2);  // waves 0-1 also compute q rows w*16..w*16+15

  const int b = blockIdx.x >> 3;     // batch
  const int chunk = blockIdx.x & 7;  // 64-token chunk within doc
  const long row0b = (long)b * LD + chunk * 64;

  if (tid < 64) dmsk[tid] = dmask[row0b + tid];

  // Fragment-mapped per-lane bases: lane (quad,lm) supplies
  // A[w*16+lm][k = kk*64 + ks*32 + quad*8 .. +7].
  const float* gA = dh + (row0b + w * 16 + lm) * (long)Hh + quad * 8;
  const float* gQ = qh + ((long)b * LQ + w * 16 + lm) * (long)Hh + quad * 8;
  // B fragment: lane (quad,lm) reads Wt[col=j*16+lm][same k-range], bf16x8.
  const short* gB = Wt + lm * Hh + quad * 8;

  f32x4 acc[8], accq[8];
#pragma unroll
  for (int j = 0; j < 8; ++j) acc[j] = (f32x4){0.f, 0.f, 0.f, 0.f};
#pragma unroll
  for (int j = 0; j < 8; ++j) accq[j] = (f32x4){0.f, 0.f, 0.f, 0.f};

  float4 ar[4], aq[4];
  // preload kk=0: ar[0..1] = ks0 pair, ar[2..3] = ks1 pair
#pragma unroll
  for (int i = 0; i < 4; ++i)
    ar[i] = *(const float4*)(gA + (i >> 1) * 32 + (i & 1) * 4);
  if (isq) {
#pragma unroll
    for (int i = 0; i < 4; ++i)
      aq[i] = *(const float4*)(gQ + (i >> 1) * 32 + (i & 1) * 4);
  }

  for (int kk = 0; kk < Hh / 64; ++kk) {
    // Build this chunk's fragments (frees ar/aq for the prefetch).
    bf16x8 fa0, fa1, fq0, fq1;
    fa0[0] = f2bf(ar[0].x); fa0[1] = f2bf(ar[0].y);
    fa0[2] = f2bf(ar[0].z); fa0[3] = f2bf(ar[0].w);
    fa0[4] = f2bf(ar[1].x); fa0[5] = f2bf(ar[1].y);
    fa0[6] = f2bf(ar[1].z); fa0[7] = f2bf(ar[1].w);
    fa1[0] = f2bf(ar[2].x); fa1[1] = f2bf(ar[2].y);
    fa1[2] = f2bf(ar[2].z); fa1[3] = f2bf(ar[2].w);
    fa1[4] = f2bf(ar[3].x); fa1[5] = f2bf(ar[3].y);
    fa1[6] = f2bf(ar[3].z); fa1[7] = f2bf(ar[3].w);
    if (isq) {
      fq0[0] = f2bf(aq[0].x); fq0[1] = f2bf(aq[0].y);
      fq0[2] = f2bf(aq[0].z); fq0[3] = f2bf(aq[0].w);
      fq0[4] = f2bf(aq[1].x); fq0[5] = f2bf(aq[1].y);
      fq0[6] = f2bf(aq[1].z); fq0[7] = f2bf(aq[1].w);
      fq1[0] = f2bf(aq[2].x); fq1[1] = f2bf(aq[2].y);
      fq1[2] = f2bf(aq[2].z); fq1[3] = f2bf(aq[2].w);
      fq1[4] = f2bf(aq[3].x); fq1[5] = f2bf(aq[3].y);
      fq1[6] = f2bf(aq[3].z); fq1[7] = f2bf(aq[3].w);
    }

    // Prefetch next K-chunk (HBM/L3 latency hides under this chunk's MFMAs).
    {
      const long go = (kk + 1 < Hh / 64) ? (long)(kk + 1) * 64 : 0;
#pragma unroll
      for (int i = 0; i < 4; ++i)
        ar[i] = *(const float4*)(gA + go + (i >> 1) * 32 + (i & 1) * 4);
      if (isq) {
#pragma unroll
        for (int i = 0; i < 4; ++i)
          aq[i] = *(const float4*)(gQ + go + (i >> 1) * 32 + (i & 1) * 4);
      }
    }

    // Per ks: batch all 8 fb loads (L2-resident Wt), then the MFMAs.
#pragma unroll
    for (int ks = 0; ks < 2; ++ks) {
      const bf16x8 fa = ks ? fa1 : fa0;
      const bf16x8 fq = ks ? fq1 : fq0;
      const long ko = (long)kk * 64 + ks * 32;
      bf16x8 fbv[8];
#pragma unroll
      for (int j = 0; j < 8; ++j)
        fbv[j] = *(const bf16x8*)(gB + j * 16 * Hh + ko);
#pragma unroll
      for (int j = 0; j < 8; ++j) {
        acc[j] = __builtin_amdgcn_mfma_f32_16x16x32_bf16(fa, fbv[j], acc[j], 0, 0, 0);
        if (isq)
          accq[j] = __builtin_amdgcn_mfma_f32_16x16x32_bf16(fq, fbv[j], accq[j], 0, 0, 0);
      }
    }
  }

  __syncthreads();  // dmsk visible; all waves done before dvt/lqt writes

  // Epilogue: bias, importance (quad butterfly), mask -> dvt LDS; waves 0-1
  // also write masked q_vecs -> lqt LDS straight from accumulators.
  float bc[8], wsv[8];
#pragma unroll
  for (int j = 0; j < 8; ++j) bc[j] = bcomp[j * 16 + lm];
#pragma unroll
  for (int j = 0; j < 8; ++j) wsv[j] = wstop[j * 16 + lm];
  const float bs = bstop[0];

#pragma unroll
  for (int r = 0; r < 4; ++r) {
    const int lrow = w * 16 + quad * 4 + r;  // chunk-local doc row
    float v[8];
#pragma unroll
    for (int j = 0; j < 8; ++j) v[j] = acc[j][r] + bc[j];
    float p = 0.f;
#pragma unroll
    for (int j = 0; j < 8; ++j) p += v[j] * wsv[j];
    p += __shfl_xor(p, 1);
    p += __shfl_xor(p, 2);
    p += __shfl_xor(p, 4);
    p += __shfl_xor(p, 8);
    const float imp = fmaxf(p + bs, 0.f);
    const float scale = imp * (float)dmsk[lrow];
#pragma unroll
    for (int j = 0; j < 8; ++j) dvt[lrow * DSTR + j * 16 + lm] = v[j] * scale;
  }
  if (isq) {
    const int qrow0 = w * 16 + quad * 4;
#pragma unroll
    for (int r = 0; r < 4; ++r) {
      const int qrow = qrow0 + r;
      const float scale = (float)qmask[b * LQ + qrow];
#pragma unroll
      for (int j = 0; j < 8; ++j)
        lqt[qrow * DSTR + j * 16 + lm] = (accq[j][r] + bc[j]) * scale;
    }
  }
  __syncthreads();  // dv + lq tiles visible

  // Score phase: thread (qt,kt) owns q rows {qt, qt+16} x doc rows kt*4..+3;
  // accumulate over c in float4 steps (zero cross-lane ops).
  const int qt = tid & 15;
  const int kt = tid >> 4;
  const int kbase = kt * 4;
  float a[2][4];
#pragma unroll
  for (int qi = 0; qi < 2; ++qi)
#pragma unroll
    for (int ki = 0; ki < 4; ++ki) a[qi][ki] = 0.f;

  for (int c = 0; c < Cc; c += 4) {
    float4 q0 = *(float4*)&lqt[qt * DSTR + c];
    float4 q1 = *(float4*)&lqt[(qt + 16) * DSTR + c];
    float4 d0 = *(float4*)&dvt[(kbase + 0) * DSTR + c];
    float4 d1 = *(float4*)&dvt[(kbase + 1) * DSTR + c];
    float4 d2 = *(float4*)&dvt[(kbase + 2) * DSTR + c];
    float4 d3 = *(float4*)&dvt[(kbase + 3) * DSTR + c];
    a[0][0] += q0.x * d0.x + q0.y * d0.y + q0.z * d0.z + q0.w * d0.w;
    a[0][1] += q0.x * d1.x + q0.y * d1.y + q0.z * d1.z + q0.w * d1.w;
    a[0][2] += q0.x * d2.x + q0.y * d2.y + q0.z * d2.z + q0.w * d2.w;
    a[0][3] += q0.x * d3.x + q0.y * d3.y + q0.z * d3.z + q0.w * d3.w;
    a[1][0] += q1.x * d0.x + q1.y * d0.y + q1.z * d0.z + q1.w * d0.w;
    a[1][1] += q1.x * d1.x + q1.y * d1.y + q1.z * d1.z + q1.w * d1.w;
    a[1][2] += q1.x * d2.x + q1.y * d2.y + q1.z * d2.z + q1.w * d2.w;
    a[1][3] += q1.x * d3.x + q1.y * d3.y + q1.z * d3.z + q1.w * d3.w;
  }
  float m0 = -1000.f, m1 = -1000.f;
#pragma unroll
  for (int ki = 0; ki < 4; ++ki) {
    if (dmsk[kbase + ki]) {
      m0 = fmaxf(m0, a[0][ki]);
      m1 = fmaxf(m1, a[1][ki]);
    }
  }
  pm[qt * 16 + kt] = m0;
  pm[(qt + 16) * 16 + kt] = m1;
  __syncthreads();
  if (tid < LQ) {
    float mx = pm[tid * 16];
#pragma unroll
    for (int t = 1; t < 16; ++t) mx = fmaxf(mx, pm[tid * 16 + t]);
    partial[((size_t)b * LQ + tid) * 8 + chunk] = mx;
  }
}

// Finalize: cls dot on raw CLS vectors, max over chunks, masked sum, merge.
__global__ __launch_bounds__(256) void k_final(
    const float* __restrict__ qh, const float* __restrict__ dh,
    const int* __restrict__ qmask, const float* __restrict__ partial,
    const float* __restrict__ merger, float* __restrict__ out) {
  const int b = blockIdx.x;
  const int tid = threadIdx.x;
  __shared__ float red[256];
  __shared__ float clss;
  const float* qc = qh + (size_t)b * LQ * Hh;  // q row 0 = CLS
  const float* dc = dh + (size_t)b * LD * Hh;  // d row 0 = CLS
  float s = 0.f;
  for (int h = tid; h < Hh; h += 256) s += qc[h] * dc[h];
  red[tid] = s;
  __syncthreads();
  for (int off = 128; off > 0; off >>= 1) {
    if (tid < off) red[tid] += red[tid + off];
    __syncthreads();
  }
  if (tid == 0) clss = red[0];
  __syncthreads();
  float t = 0.f;
  if (tid < LQ) {
    const float* pp = partial + ((size_t)b * LQ + tid) * 8;
    float mx = pp[0];
#pragma unroll
    for (int c = 1; c < 8; ++c) mx = fmaxf(mx, pp[c]);
    if (qmask[b * LQ + tid]) t = mx;
  }
  red[tid] = t;
  __syncthreads();
  for (int off = 128; off > 0; off >>= 1) {
    if (tid < off) red[tid] += red[tid + off];
    __syncthreads();
  }
  if (tid == 0) {
    float w = 1.f / (1.f + expf(-merger[0]));
    float cs = clss * w;
    float ts = red[0] * (1.f - w);
    out[b] = cs + ts;        // score
    out[Bb + b] = cs;        // cls_score
    out[2 * Bb + b] = ts;    // term_score
  }
}

extern "C" void kernel_launch(void* const* d_in, const int* in_sizes, int n_in,
                              void* d_out, int out_size, void* d_ws, size_t ws_size,
                              hipStream_t stream) {
  const float* qh  = (const float*)d_in[0];  // (B,LQ,H)
  const float* dh  = (const float*)d_in[1];  // (B,LD,H)
  const int*   qm  = (const int*)d_in[2];    // (B,LQ)
  const int*   dm  = (const int*)d_in[3];    // (B,LD)
  const float* W   = (const float*)d_in[4];  // (H,C)
  const float* bc  = (const float*)d_in[5];  // (C)
  const float* wst = (const float*)d_in[6];  // (C,1)
  const float* bst = (const float*)d_in[7];  // (1)
  const float* mrg = (const float*)d_in[8];  // (1)
  float* out = (float*)d_out;                // 3*B floats

  char* ws = (char*)d_ws;
  short* Wt  = (short*)ws;              // 192 KB bf16 W^T
  float* prt = (float*)(ws + 196608);   // 128 KB partial max

  k_wt<<<(Hh * Cc) / 256, 256, 0, stream>>>(W, Wt);
  k_fused<<<DBLOCKS, 256, 0, stream>>>(dh, qh, Wt, bc, qm, dm, wst, bst, prt);
  k_final<<<Bb, 256, 0, stream>>>(qh, dh, qm, prt, mrg, out);
}

// Round 6
// 325.225 us; speedup vs baseline: 1.2068x; 1.2068x over previous
//
#include <hip/hip_runtime.h>
#include <hip/hip_bf16.h>

#define Bb 128
#define LQ 32
#define LD 512
#define Hh 768
#define Cc 128

#define DBLOCKS ((Bb * LD) / 64)   // 1024 doc blocks (64 rows each)

typedef short bf16x8 __attribute__((ext_vector_type(8)));
typedef short bf16x4 __attribute__((ext_vector_type(4)));
typedef float f32x4 __attribute__((ext_vector_type(4)));

__device__ __forceinline__ short f2bf(float f) {
  union { float f; unsigned u; } v;
  v.f = f;
  unsigned u = v.u + (0x7FFFu + ((v.u >> 16) & 1u));  // RNE
  return (short)(u >> 16);
}

// K0: W (H,C) fp32 -> Wt (C,H) bf16 (transposed so B-chunks are row-contiguous)
__global__ __launch_bounds__(256) void k_wt(const float* __restrict__ W,
                                            short* __restrict__ Wt) {
  int idx = blockIdx.x * 256 + threadIdx.x;  // grid covers H*C exactly
  int h = idx >> 7;   // / 128
  int c = idx & 127;
  Wt[c * Hh + h] = f2bf(W[idx]);
}

// Fully fused: doc projection + query projection + importance + scores +
// partial max. One block per (batch, 64-doc-token chunk).
//
// Structure = round-4 (LDS-staged, coalesced, 2-barrier K-loop; round-5
// proved de-staging is a coalescing disaster: 64 cache lines/instr, +57 MB
// fetch, 1.8x slower). Change vs round-4: A (dh, the HBM stream, ~900 cyc)
// is register-prefetched TWO chunks deep, so the pack-phase vmcnt wait --
// which sits inside the barrier critical section and was the dominant stall
// (counters: all pipes <17% busy) -- has ~2 full iterations to cover. B (Wt,
// L2-resident ~200 cyc) and Q (qh, L3-hot, waves 0-1 only) stay 1-deep.
// Bit-identical arithmetic to round-4 (same f2bf/pack/MFMA sequence).
//
// LDS layout (52992 B total, 3 blocks/CU):
//   [0,     33792) : GEMM staging (A 9216 + B 20480) -- then dv[64][132] fp32
//   [33792, 50688) : lq[32][132] fp32 (written by q-epilogue)
//   [50688, 50944) : dmsk[64]
//   [50944, 52992) : pm[32][16]
__global__ __launch_bounds__(256, 4) void k_fused(
    const float* __restrict__ dh, const float* __restrict__ qh,
    const short* __restrict__ Wt, const float* __restrict__ bcomp,
    const int* __restrict__ qmask, const int* __restrict__ dmask,
    const float* __restrict__ wstop, const float* __restrict__ bstop,
    float* __restrict__ partial) {
  constexpr int ASTR = 144;
  constexpr int BSTR = 160;
  constexpr int ASZ = 64 * ASTR;     // 9216
  constexpr int DSTR = 132;          // fp32 row stride (+4 pad: 2-way max)
  constexpr int DVB = 64 * DSTR * 4; // 33792 (>= ASZ + BSZ = 29696)
  constexpr int NK = Hh / 64;        // 12 K-chunks
  __shared__ __align__(16) char smem[DVB + 32 * DSTR * 4 + 256 + 2048];

  char* bufA = smem;
  char* bufB = smem + ASZ;
  float* dvt = (float*)smem;                       // [64][132], after GEMM
  float* lqt = (float*)(smem + DVB);               // [32][132]
  int* dmsk = (int*)(smem + DVB + 32 * DSTR * 4);  // [64]
  float* pm = (float*)(smem + DVB + 32 * DSTR * 4 + 256);  // [32][16]

  const int tid = threadIdx.x;
  const int w = tid >> 6;
  const int lane = tid & 63;
  const int quad = lane >> 4;
  const int lm = lane & 15;
  const bool isq = (w < 2);  // waves 0-1 also compute q rows w*16..w*16+15

  const int b = blockIdx.x >> 3;     // batch
  const int chunk = blockIdx.x & 7;  // 64-token chunk within doc
  const long row0b = (long)b * LD + chunk * 64;

  if (tid < 64) dmsk[tid] = dmask[row0b + tid];

  const float* gA = dh + (row0b + w * 16 + (lane >> 4)) * (long)Hh + (lane & 15) * 4;
  const short* gB = Wt + (w * 32 + (lane >> 3)) * Hh + (lane & 7) * 8;
  const float* gQ = qh + ((long)b * LQ + w * 16 + lm) * Hh + quad * 8;
  const int aoff = (w * 16 + (lane >> 4)) * ASTR + (lane & 15) * 8;
  const int boff = (w * 32 + (lane >> 3)) * BSTR + (lane & 7) * 16;

  f32x4 acc[8], accq[8];
#pragma unroll
  for (int j = 0; j < 8; ++j) acc[j] = (f32x4){0.f, 0.f, 0.f, 0.f};
#pragma unroll
  for (int j = 0; j < 8; ++j) accq[j] = (f32x4){0.f, 0.f, 0.f, 0.f};

  float4 arA[4], arB[4], aq[4];
  bf16x8 br[4];
  // Preload: A chunks 0 AND 1 (2-deep); B chunk 0, Q chunk 0 (1-deep).
#pragma unroll
  for (int i = 0; i < 4; ++i) arA[i] = *(const float4*)(gA + i * 4 * Hh);
#pragma unroll
  for (int i = 0; i < 4; ++i) arB[i] = *(const float4*)(gA + 64 + i * 4 * Hh);
#pragma unroll
  for (int i = 0; i < 4; ++i) br[i] = *(const bf16x8*)(gB + i * 8 * Hh);
  if (isq) {
#pragma unroll
    for (int i = 0; i < 4; ++i)
      aq[i] = *(const float4*)(gQ + (i >> 1) * 32 + (i & 1) * 4);
  }

  // One K-iteration; ar = the A-register buffer holding chunk kk's data
  // (refilled here with chunk kk+2). Static parity via unroll-by-2 caller.
  auto iter = [&](int kk, float4 (&ar)[4]) {
    __syncthreads();  // previous chunk's LDS readers done
    // pack + write chunk kk regs -> LDS
#pragma unroll
    for (int i = 0; i < 4; ++i) {
      bf16x4 p;
      p[0] = f2bf(ar[i].x); p[1] = f2bf(ar[i].y);
      p[2] = f2bf(ar[i].z); p[3] = f2bf(ar[i].w);
      *(bf16x4*)(bufA + aoff + i * 4 * ASTR) = p;
    }
#pragma unroll
    for (int i = 0; i < 4; ++i)
      *(bf16x8*)(bufB + boff + i * 8 * BSTR) = br[i];
    __syncthreads();  // LDS tile visible

    // Build this chunk's q fragments from aq NOW (before prefetch clobbers).
    bf16x8 fq0, fq1;
    if (isq) {
      fq0[0] = f2bf(aq[0].x); fq0[1] = f2bf(aq[0].y);
      fq0[2] = f2bf(aq[0].z); fq0[3] = f2bf(aq[0].w);
      fq0[4] = f2bf(aq[1].x); fq0[5] = f2bf(aq[1].y);
      fq0[6] = f2bf(aq[1].z); fq0[7] = f2bf(aq[1].w);
      fq1[0] = f2bf(aq[2].x); fq1[1] = f2bf(aq[2].y);
      fq1[2] = f2bf(aq[2].z); fq1[3] = f2bf(aq[2].w);
      fq1[4] = f2bf(aq[3].x); fq1[5] = f2bf(aq[3].y);
      fq1[6] = f2bf(aq[3].z); fq1[7] = f2bf(aq[3].w);
    }

    // Issue prefetches: A two chunks ahead (HBM latency needs ~2 phases),
    // B/Q one chunk ahead (L2/L3-resident).
    {
      const long goA = (kk + 2 < NK) ? (long)(kk + 2) * 64 : 0;
#pragma unroll
      for (int i = 0; i < 4; ++i)
        ar[i] = *(const float4*)(gA + goA + i * 4 * Hh);
      const long go1 = (kk + 1 < NK) ? (long)(kk + 1) * 64 : 0;
#pragma unroll
      for (int i = 0; i < 4; ++i)
        br[i] = *(const bf16x8*)(gB + go1 + i * 8 * Hh);
      if (isq) {
#pragma unroll
        for (int i = 0; i < 4; ++i)
          aq[i] = *(const float4*)(gQ + go1 + (i >> 1) * 32 + (i & 1) * 4);
      }
    }

    // compute chunk kk: doc 16x128 per wave; waves 0-1 add q 16x128 reusing fb
#pragma unroll
    for (int ks = 0; ks < 2; ++ks) {
      bf16x8 fa = *(const bf16x8*)(bufA + (w * 16 + lm) * ASTR + ks * 64 + quad * 16);
      const bf16x8 fqk = (ks == 0) ? fq0 : fq1;
#pragma unroll
      for (int j = 0; j < 8; ++j) {
        bf16x8 fb = *(const bf16x8*)(bufB + (j * 16 + lm) * BSTR + ks * 64 + quad * 16);
        acc[j] = __builtin_amdgcn_mfma_f32_16x16x32_bf16(fa, fb, acc[j], 0, 0, 0);
        if (isq)
          accq[j] = __builtin_amdgcn_mfma_f32_16x16x32_bf16(fqk, fb, accq[j], 0, 0, 0);
      }
    }
  };

  for (int kp = 0; kp < NK / 2; ++kp) {
    iter(2 * kp, arA);
    iter(2 * kp + 1, arB);
  }

  __syncthreads();  // all staging reads done -> safe to overwrite with dv

  // Epilogue: bias, importance (quad butterfly), mask -> dvt LDS; waves 0-1
  // also write masked q_vecs -> lqt LDS straight from accumulators.
  float bc[8], wsv[8];
#pragma unroll
  for (int j = 0; j < 8; ++j) bc[j] = bcomp[j * 16 + lm];
#pragma unroll
  for (int j = 0; j < 8; ++j) wsv[j] = wstop[j * 16 + lm];
  const float bs = bstop[0];

#pragma unroll
  for (int r = 0; r < 4; ++r) {
    const int lrow = w * 16 + quad * 4 + r;  // chunk-local doc row
    float v[8];
#pragma unroll
    for (int j = 0; j < 8; ++j) v[j] = acc[j][r] + bc[j];
    float p = 0.f;
#pragma unroll
    for (int j = 0; j < 8; ++j) p += v[j] * wsv[j];
    p += __shfl_xor(p, 1);
    p += __shfl_xor(p, 2);
    p += __shfl_xor(p, 4);
    p += __shfl_xor(p, 8);
    const float imp = fmaxf(p + bs, 0.f);
    const float scale = imp * (float)dmsk[lrow];
#pragma unroll
    for (int j = 0; j < 8; ++j) dvt[lrow * DSTR + j * 16 + lm] = v[j] * scale;
  }
  if (isq) {
    const int qrow0 = w * 16 + quad * 4;
#pragma unroll
    for (int r = 0; r < 4; ++r) {
      const int qrow = qrow0 + r;
      const float scale = (float)qmask[b * LQ + qrow];
#pragma unroll
      for (int j = 0; j < 8; ++j)
        lqt[qrow * DSTR + j * 16 + lm] = (accq[j][r] + bc[j]) * scale;
    }
  }
  __syncthreads();  // dv + lq tiles visible

  // Score phase: thread (qt,kt) owns q rows {qt, qt+16} x doc rows kt*4..+3;
  // accumulate over c in float4 steps (zero cross-lane ops).
  const int qt = tid & 15;
  const int kt = tid >> 4;
  const int kbase = kt * 4;
  float a[2][4];
#pragma unroll
  for (int qi = 0; qi < 2; ++qi)
#pragma unroll
    for (int ki = 0; ki < 4; ++ki) a[qi][ki] = 0.f;

  for (int c = 0; c < Cc; c += 4) {
    float4 q0 = *(float4*)&lqt[qt * DSTR + c];
    float4 q1 = *(float4*)&lqt[(qt + 16) * DSTR + c];
    float4 d0 = *(float4*)&dvt[(kbase + 0) * DSTR + c];
    float4 d1 = *(float4*)&dvt[(kbase + 1) * DSTR + c];
    float4 d2 = *(float4*)&dvt[(kbase + 2) * DSTR + c];
    float4 d3 = *(float4*)&dvt[(kbase + 3) * DSTR + c];
    a[0][0] += q0.x * d0.x + q0.y * d0.y + q0.z * d0.z + q0.w * d0.w;
    a[0][1] += q0.x * d1.x + q0.y * d1.y + q0.z * d1.z + q0.w * d1.w;
    a[0][2] += q0.x * d2.x + q0.y * d2.y + q0.z * d2.z + q0.w * d2.w;
    a[0][3] += q0.x * d3.x + q0.y * d3.y + q0.z * d3.z + q0.w * d3.w;
    a[1][0] += q1.x * d0.x + q1.y * d0.y + q1.z * d0.z + q1.w * d0.w;
    a[1][1] += q1.x * d1.x + q1.y * d1.y + q1.z * d1.z + q1.w * d1.w;
    a[1][2] += q1.x * d2.x + q1.y * d2.y + q1.z * d2.z + q1.w * d2.w;
    a[1][3] += q1.x * d3.x + q1.y * d3.y + q1.z * d3.z + q1.w * d3.w;
  }
  float m0 = -1000.f, m1 = -1000.f;
#pragma unroll
  for (int ki = 0; ki < 4; ++ki) {
    if (dmsk[kbase + ki]) {
      m0 = fmaxf(m0, a[0][ki]);
      m1 = fmaxf(m1, a[1][ki]);
    }
  }
  pm[qt * 16 + kt] = m0;
  pm[(qt + 16) * 16 + kt] = m1;
  __syncthreads();
  if (tid < LQ) {
    float mx = pm[tid * 16];
#pragma unroll
    for (int t = 1; t < 16; ++t) mx = fmaxf(mx, pm[tid * 16 + t]);
    partial[((size_t)b * LQ + tid) * 8 + chunk] = mx;
  }
}

// Finalize: cls dot on raw CLS vectors, max over chunks, masked sum, merge.
__global__ __launch_bounds__(256) void k_final(
    const float* __restrict__ qh, const float* __restrict__ dh,
    const int* __restrict__ qmask, const float* __restrict__ partial,
    const float* __restrict__ merger, float* __restrict__ out) {
  const int b = blockIdx.x;
  const int tid = threadIdx.x;
  __shared__ float red[256];
  __shared__ float clss;
  const float* qc = qh + (size_t)b * LQ * Hh;  // q row 0 = CLS
  const float* dc = dh + (size_t)b * LD * Hh;  // d row 0 = CLS
  float s = 0.f;
  for (int h = tid; h < Hh; h += 256) s += qc[h] * dc[h];
  red[tid] = s;
  __syncthreads();
  for (int off = 128; off > 0; off >>= 1) {
    if (tid < off) red[tid] += red[tid + off];
    __syncthreads();
  }
  if (tid == 0) clss = red[0];
  __syncthreads();
  float t = 0.f;
  if (tid < LQ) {
    const float* pp = partial + ((size_t)b * LQ + tid) * 8;
    float mx = pp[0];
#pragma unroll
    for (int c = 1; c < 8; ++c) mx = fmaxf(mx, pp[c]);
    if (qmask[b * LQ + tid]) t = mx;
  }
  red[tid] = t;
  __syncthreads();
  for (int off = 128; off > 0; off >>= 1) {
    if (tid < off) red[tid] += red[tid + off];
    __syncthreads();
  }
  if (tid == 0) {
    float w = 1.f / (1.f + expf(-merger[0]));
    float cs = clss * w;
    float ts = red[0] * (1.f - w);
    out[b] = cs + ts;        // score
    out[Bb + b] = cs;        // cls_score
    out[2 * Bb + b] = ts;    // term_score
  }
}

extern "C" void kernel_launch(void* const* d_in, const int* in_sizes, int n_in,
                              void* d_out, int out_size, void* d_ws, size_t ws_size,
                              hipStream_t stream) {
  const float* qh  = (const float*)d_in[0];  // (B,LQ,H)
  const float* dh  = (const float*)d_in[1];  // (B,LD,H)
  const int*   qm  = (const int*)d_in[2];    // (B,LQ)
  const int*   dm  = (const int*)d_in[3];    // (B,LD)
  const float* W   = (const float*)d_in[4];  // (H,C)
  const float* bc  = (const float*)d_in[5];  // (C)
  const float* wst = (const float*)d_in[6];  // (C,1)
  const float* bst = (const float*)d_in[7];  // (1)
  const float* mrg = (const float*)d_in[8];  // (1)
  float* out = (float*)d_out;                // 3*B floats

  char* ws = (char*)d_ws;
  short* Wt  = (short*)ws;              // 192 KB bf16 W^T
  float* prt = (float*)(ws + 196608);   // 128 KB partial max

  k_wt<<<(Hh * Cc) / 256, 256, 0, stream>>>(W, Wt);
  k_fused<<<DBLOCKS, 256, 0, stream>>>(dh, qh, Wt, bc, qm, dm, wst, bst, prt);
  k_final<<<Bb, 256, 0, stream>>>(qh, dh, qm, prt, mrg, out);
}